// Round 4
// baseline (232.534 us; speedup 1.0000x reference)
//
#include <hip/hip_runtime.h>
#include <hip/hip_bf16.h>

// ---------------------------------------------------------------------------
// CapsNet forward, fp32. B=512.
// convs: one block per batch elem, padded input in LDS, fused relu+pool.
// routing1: register-resident, lane==route(64), wave butterflies, G=8 batch
//           elems per block; W pre-transposed to [n][c][r][o].
// routing2+fc: register-resident, lane=(n-half, r=32), 32-lane butterflies.
// ---------------------------------------------------------------------------

template<int CIN, int COUT, int HIN, int NO>
__global__ __launch_bounds__(256)
void conv_relu_pool(const float* __restrict__ in, const float* __restrict__ w,
                    const float* __restrict__ bias, float* __restrict__ out)
{
    constexpr int HOUT = HIN / 2;
    constexpr int PR = HIN + 2;
    constexpr int PC = (HIN + 2 + 3) & ~3;
    constexpr int NS = HIN / 8;
    constexpr int NOP = COUT / NO;
    constexpr int NTASK = NOP * HOUT * NS;
    constexpr int XWORDS = CIN * PR * PC;
    constexpr int WWORDS = CIN * 9 * COUT;

    __shared__ float xin[CIN][PR][PC];
    __shared__ float wt[WWORDS];                // [c][k][o]
    __shared__ float bl[COUT];

    const int tid = threadIdx.x;
    const int b   = blockIdx.x;

    for (int i = tid; i < XWORDS; i += 256) ((float*)xin)[i] = 0.f;
    for (int i = tid; i < WWORDS; i += 256) {
        int o = i % COUT, k = (i / COUT) % 9, c = i / (COUT * 9);
        wt[i] = w[(o * CIN + c) * 9 + k];
    }
    if (tid < COUT) bl[tid] = bias[tid];
    __syncthreads();

    const float4* gin = (const float4*)(in + (size_t)b * CIN * HIN * HIN);
    constexpr int CHUNKS = CIN * HIN * (HIN / 4);
    for (int i = tid; i < CHUNKS; i += 256) {
        float4 v = gin[i];
        int ch = i % (HIN / 4);
        int y  = (i / (HIN / 4)) % HIN;
        int c  = i / ((HIN / 4) * HIN);
        float* dst = &xin[c][y + 1][ch * 4 + 1];
        dst[0] = v.x; dst[1] = v.y; dst[2] = v.z; dst[3] = v.w;
    }
    __syncthreads();

    for (int task = tid; task < NTASK; task += 256) {
        const int s  = task % NS;
        const int py = (task / NS) % HOUT;
        const int o0 = (task / (NS * HOUT)) * NO;
        const int X0 = s * 8;

        float acc[NO][2][8];
#pragma unroll
        for (int n = 0; n < NO; ++n)
#pragma unroll
            for (int q = 0; q < 2; ++q)
#pragma unroll
                for (int j = 0; j < 8; ++j) acc[n][q][j] = 0.f;

        for (int c = 0; c < CIN; ++c) {
            float rows[4][12];
#pragma unroll
            for (int rr = 0; rr < 4; ++rr) {
                const float4* src = (const float4*)&xin[c][2 * py + rr][X0];
#pragma unroll
                for (int j = 0; j < 3; ++j) {
                    float4 v = src[j];
                    rows[rr][j * 4 + 0] = v.x; rows[rr][j * 4 + 1] = v.y;
                    rows[rr][j * 4 + 2] = v.z; rows[rr][j * 4 + 3] = v.w;
                }
            }
            const float* wc = wt + c * 9 * COUT;
#pragma unroll
            for (int ky = 0; ky < 3; ++ky) {
#pragma unroll
                for (int n = 0; n < NO; ++n) {
                    const float w0 = wc[(ky * 3 + 0) * COUT + o0 + n];
                    const float w1 = wc[(ky * 3 + 1) * COUT + o0 + n];
                    const float w2 = wc[(ky * 3 + 2) * COUT + o0 + n];
#pragma unroll
                    for (int j = 0; j < 8; ++j) {
                        acc[n][0][j] = fmaf(rows[ky][j],     w0, acc[n][0][j]);
                        acc[n][0][j] = fmaf(rows[ky][j + 1], w1, acc[n][0][j]);
                        acc[n][0][j] = fmaf(rows[ky][j + 2], w2, acc[n][0][j]);
                        acc[n][1][j] = fmaf(rows[ky + 1][j],     w0, acc[n][1][j]);
                        acc[n][1][j] = fmaf(rows[ky + 1][j + 1], w1, acc[n][1][j]);
                        acc[n][1][j] = fmaf(rows[ky + 1][j + 2], w2, acc[n][1][j]);
                    }
                }
            }
        }
#pragma unroll
        for (int n = 0; n < NO; ++n) {
            const float bv = bl[o0 + n];
            float4 ov;
            float* p = (float*)&ov;
#pragma unroll
            for (int j = 0; j < 4; ++j) {
                float m = fmaxf(fmaxf(acc[n][0][2 * j], acc[n][0][2 * j + 1]),
                                fmaxf(acc[n][1][2 * j], acc[n][1][2 * j + 1]));
                p[j] = fmaxf(m + bv, 0.f);
            }
            float* po = out + (((size_t)b * COUT + o0 + n) * HOUT + py) * HOUT + s * 4;
            *(float4*)po = ov;
        }
    }
}

// W[n][r][c][o] -> Wt[n][c][r][o]  (n=32, r=64, c=32, o=8), float4 granules.
__global__ __launch_bounds__(256)
void transpose_w1(const float* __restrict__ W, float* __restrict__ Wt)
{
    int idx = blockIdx.x * 256 + threadIdx.x;
    if (idx >= 32 * 32 * 64 * 2) return;
    int half = idx & 1;
    int r    = (idx >> 1) & 63;
    int c    = (idx >> 7) & 31;
    int n    = idx >> 12;
    ((float4*)Wt)[idx] =
        ((const float4*)W)[(((n * 64 + r) * 32 + c) << 1) + half];
}

// Routing stage 1, register-resident. lane == r; wave owns one n; G=8 b/block.
__global__ __launch_bounds__(256)
void routing1_reg(const float* __restrict__ h3, const float* __restrict__ Wt,
                  float* __restrict__ v1)
{
    constexpr int C = 32, R = 64, O = 8, G = 8;
    const int lane = threadIdx.x & 63;
    const int n    = blockIdx.y * 4 + (threadIdx.x >> 6);
    const int b0   = blockIdx.x * G;

    float u[G][O];
#pragma unroll
    for (int g = 0; g < G; ++g)
#pragma unroll
        for (int o = 0; o < O; ++o) u[g][o] = 0.f;

    const float4* wp = (const float4*)Wt + (size_t)n * C * R * 2;
    const float* xb = h3 + (size_t)b0 * (C * R) + lane;

#pragma unroll 2
    for (int c = 0; c < C; ++c) {
        float xv[G];
#pragma unroll
        for (int g = 0; g < G; ++g) xv[g] = xb[(size_t)g * (C * R) + c * R];
        float4 w0 = wp[(c * R + lane) * 2];
        float4 w1 = wp[(c * R + lane) * 2 + 1];
#pragma unroll
        for (int g = 0; g < G; ++g) {
            u[g][0] = fmaf(xv[g], w0.x, u[g][0]);
            u[g][1] = fmaf(xv[g], w0.y, u[g][1]);
            u[g][2] = fmaf(xv[g], w0.z, u[g][2]);
            u[g][3] = fmaf(xv[g], w0.w, u[g][3]);
            u[g][4] = fmaf(xv[g], w1.x, u[g][4]);
            u[g][5] = fmaf(xv[g], w1.y, u[g][5]);
            u[g][6] = fmaf(xv[g], w1.z, u[g][6]);
            u[g][7] = fmaf(xv[g], w1.w, u[g][7]);
        }
    }

    float bij[G];
#pragma unroll
    for (int g = 0; g < G; ++g) bij[g] = 0.f;
    float s[G][O];

    for (int it = 0; it < 3; ++it) {
        float cc[G];
#pragma unroll
        for (int g = 0; g < G; ++g) {
            float mx = bij[g];
#pragma unroll
            for (int w = 1; w < 64; w <<= 1) mx = fmaxf(mx, __shfl_xor(mx, w, 64));
            float e = __expf(bij[g] - mx);
            float sum = e;
#pragma unroll
            for (int w = 1; w < 64; w <<= 1) sum += __shfl_xor(sum, w, 64);
            cc[g] = e / sum;
        }
#pragma unroll
        for (int g = 0; g < G; ++g)
#pragma unroll
            for (int o = 0; o < O; ++o) s[g][o] = cc[g] * u[g][o];
#pragma unroll
        for (int w = 1; w < 64; w <<= 1)
#pragma unroll
            for (int g = 0; g < G; ++g)
#pragma unroll
                for (int o = 0; o < O; ++o) s[g][o] += __shfl_xor(s[g][o], w, 64);
#pragma unroll
        for (int g = 0; g < G; ++g) {
            float nr = 0.f;
#pragma unroll
            for (int o = 0; o < O; ++o) nr = fmaf(s[g][o], s[g][o], nr);
            float scale = nr / (1.f + nr) / sqrtf(nr + 1e-9f);
#pragma unroll
            for (int o = 0; o < O; ++o) s[g][o] *= scale;   // s is now v
            if (it < 2) {
                float d = 0.f;
#pragma unroll
                for (int o = 0; o < O; ++o) d = fmaf(u[g][o], s[g][o], d);
                bij[g] += d;
            }
        }
    }
    // each lane writes one (g,o); values identical across lanes -> static select
    float outv = 0.f;
#pragma unroll
    for (int g = 0; g < G; ++g)
#pragma unroll
        for (int o = 0; o < O; ++o)
            outv = (lane == g * O + o) ? s[g][o] : outv;
    v1[(size_t)(b0 + (lane >> 3)) * 256 + n * 8 + (lane & 7)] = outv;
}

// Routing stage 2 + FC, register-resident. One block per b, 4 waves.
// lane = (nh, r): nh = lane>>5 selects n within pair, r = lane&31 (R=32).
// wave wv covers n = wv*4 + p*2 + nh for p=0,1 (n==15 duplicate is masked).
__global__ __launch_bounds__(256)
void routing2_fc(const float* __restrict__ v1, const float* __restrict__ W,
                 const float* __restrict__ fcw, const float* __restrict__ fcb,
                 float* __restrict__ out)
{
    constexpr int R = 32, C = 8, O = 16;
    __shared__ float vv[240];

    const int t  = threadIdx.x;
    const int b  = blockIdx.x;
    const int wv = t >> 6;
    const int lane = t & 63;
    const int nh = lane >> 5;
    const int r  = lane & 31;

    const float4* xr = (const float4*)(v1 + (size_t)b * 256 + r * 8);
    float4 x0 = xr[0], x1 = xr[1];
    float xv[8] = {x0.x, x0.y, x0.z, x0.w, x1.x, x1.y, x1.z, x1.w};

    float u[2][O];
    int nn[2];
#pragma unroll
    for (int p = 0; p < 2; ++p) {
        int n = wv * 4 + p * 2 + nh;
        nn[p] = n;
        int ncl = n < 15 ? n : 14;
        const float4* wp = (const float4*)(W + ((size_t)(ncl * R + r) * C) * O);
#pragma unroll
        for (int o = 0; o < O; ++o) u[p][o] = 0.f;
#pragma unroll
        for (int c = 0; c < C; ++c) {
#pragma unroll
            for (int j = 0; j < 4; ++j) {
                float4 w4 = wp[c * 4 + j];
                u[p][j * 4 + 0] = fmaf(xv[c], w4.x, u[p][j * 4 + 0]);
                u[p][j * 4 + 1] = fmaf(xv[c], w4.y, u[p][j * 4 + 1]);
                u[p][j * 4 + 2] = fmaf(xv[c], w4.z, u[p][j * 4 + 2]);
                u[p][j * 4 + 3] = fmaf(xv[c], w4.w, u[p][j * 4 + 3]);
            }
        }
    }

    float bij[2] = {0.f, 0.f};
    float s[2][O];
    for (int it = 0; it < 3; ++it) {
#pragma unroll
        for (int p = 0; p < 2; ++p) {
            float mx = bij[p];
#pragma unroll
            for (int w = 1; w < 32; w <<= 1) mx = fmaxf(mx, __shfl_xor(mx, w, 32));
            float e = __expf(bij[p] - mx);
            float sum = e;
#pragma unroll
            for (int w = 1; w < 32; w <<= 1) sum += __shfl_xor(sum, w, 32);
            float cc = e / sum;
#pragma unroll
            for (int o = 0; o < O; ++o) s[p][o] = cc * u[p][o];
        }
#pragma unroll
        for (int w = 1; w < 32; w <<= 1)
#pragma unroll
            for (int p = 0; p < 2; ++p)
#pragma unroll
                for (int o = 0; o < O; ++o) s[p][o] += __shfl_xor(s[p][o], w, 32);
#pragma unroll
        for (int p = 0; p < 2; ++p) {
            float nr = 0.f;
#pragma unroll
            for (int o = 0; o < O; ++o) nr = fmaf(s[p][o], s[p][o], nr);
            float scale = nr / (1.f + nr) / sqrtf(nr + 1e-9f);
#pragma unroll
            for (int o = 0; o < O; ++o) s[p][o] *= scale;   // s is now v
            if (it < 2) {
                float d = 0.f;
#pragma unroll
                for (int o = 0; o < O; ++o) d = fmaf(u[p][o], s[p][o], d);
                bij[p] += d;
            }
        }
    }
#pragma unroll
    for (int p = 0; p < 2; ++p) {
        float outv = 0.f;
#pragma unroll
        for (int o = 0; o < O; ++o) outv = (r == o) ? s[p][o] : outv;
        if (r < O && nn[p] < 15) vv[nn[p] * O + r] = outv;
    }
    __syncthreads();
    if (t < 240) {
        int j = t >> 4, k0 = t & 15;
        float acc = 0.f;
        for (int k = k0; k < 240; k += 16) acc = fmaf(vv[k], fcw[j * 240 + k], acc);
#pragma unroll
        for (int w = 1; w < 16; w <<= 1) acc += __shfl_xor(acc, w, 16);
        if (k0 == 0) out[(size_t)b * 15 + j] = acc + fcb[j];
    }
}

extern "C" void kernel_launch(void* const* d_in, const int* in_sizes, int n_in,
                              void* d_out, int out_size, void* d_ws, size_t ws_size,
                              hipStream_t stream) {
    const float* x    = (const float*)d_in[0];
    const float* w1   = (const float*)d_in[1];
    const float* b1   = (const float*)d_in[2];
    const float* w2   = (const float*)d_in[3];
    const float* b2   = (const float*)d_in[4];
    const float* w3   = (const float*)d_in[5];
    const float* b3   = (const float*)d_in[6];
    const float* rw1  = (const float*)d_in[7];
    const float* rw2  = (const float*)d_in[8];
    const float* fcw  = (const float*)d_in[9];
    const float* fcb  = (const float*)d_in[10];
    float* out = (float*)d_out;

    const int B = 512;
    float* ws = (float*)d_ws;
    float* h1 = ws;                                  // [512,8,32,32]
    float* h2 = h1 + (size_t)B * 8 * 32 * 32;        // [512,16,16,16] (dead after conv3)
    float* h3 = h2 + (size_t)B * 16 * 16 * 16;       // [512,32,8,8]
    float* v1 = h3 + (size_t)B * 32 * 8 * 8;         // [512,32,8]
    float* Wt = h2;                                  // rw1 transposed, reuses h2

    conv_relu_pool<3, 8, 64, 4><<<B, 256, 0, stream>>>(x, w1, b1, h1);
    conv_relu_pool<8, 16, 32, 4><<<B, 256, 0, stream>>>(h1, w2, b2, h2);
    conv_relu_pool<16, 32, 16, 2><<<B, 256, 0, stream>>>(h2, w3, b3, h3);
    transpose_w1<<<(32 * 32 * 64 * 2 + 255) / 256, 256, 0, stream>>>(rw1, Wt);
    {
        dim3 grid(B / 8, 8);
        routing1_reg<<<grid, 256, 0, stream>>>(h3, Wt, v1);
    }
    routing2_fc<<<B, 256, 0, stream>>>(v1, rw2, fcw, fcb, out);
}